// Round 9
// baseline (643.902 us; speedup 1.0000x reference)
//
#include <hip/hip_runtime.h>
#include <hip/hip_cooperative_groups.h>
#include <math.h>

namespace cg = cooperative_groups;

#define D_MODEL 2048
#define KB_ 64
#define NCHUNK 32

typedef __bf16 bf16;
typedef __attribute__((ext_vector_type(8))) __bf16 bf16x8;
typedef __attribute__((ext_vector_type(4))) __bf16 bf16x4;
typedef __attribute__((ext_vector_type(4))) float f32x4;

// ---- workspace layout (float offsets) ----
#define OFF_COEFFS 0                           // [32][64][2048]
#define OFF_NSQ    (32 * 64 * 2048)            // [32][64][32] per-dtile sumsq partials
#define OFF_NORMS  (OFF_NSQ + 32 * 64 * 32)    // [32][64]
#define OFF_PARTR  (OFF_NORMS + 2048)          // [32][2048]
#define OFF_PARTI  (OFF_PARTR + 32 * 2048)     // [32][2048]
#define OFF_CTX    (OFF_PARTI + 32 * 2048)     // [2048]
#define OFF_CHEB2  (OFF_CTX + 2048)            // 32768 bf16 = 16384 floats

// ===========================================================================
// Fused cooperative kernel, grid = 512 x 256 (2 blocks/CU — guaranteed
// co-resident at <=256 regs, 9.6 KB LDS). Phase 1 is grid-strided over the
// 1024 (dt, c) tiles.
// ===========================================================================
__global__ __launch_bounds__(256, 2) void fused_all(
    const float* __restrict__ scan, const float* __restrict__ buf,
    const float* __restrict__ rr, const float* __restrict__ ri,
    const float* __restrict__ wbands, const float* __restrict__ Wp,
    const float* __restrict__ gate, const float* __restrict__ cheby,
    float* __restrict__ dout, float* __restrict__ coeffs,
    float* __restrict__ nsq_part, float* __restrict__ norms,
    float* __restrict__ part_r, float* __restrict__ part_i,
    float* __restrict__ ctx, bf16* __restrict__ cheb2)
{
  cg::grid_group grid = cg::this_grid();
  const int b = blockIdx.x;
  const int tid = threadIdx.x;

  __shared__ bf16 Bs[64 * 72];       // phase 1
  __shared__ float sm64[64];         // phase 2 inv_s / phase 3 cn_s
  __shared__ float red[4];           // phase 2 delta reduction
  __shared__ int top_s[8];           // phase 3
  __shared__ float wgt_s[8];         // phase 3

  // ---- Phase 0: cheby -> bf16 ----
  if (b < 128) {
    int flat = b * 256 + tid;
    cheb2[flat] = (bf16)cheby[flat];
  }
  __threadfence();
  grid.sync();

  // ---- Phase 1: coeffs tiles (R4 k1 form), grid-stride over 1024 tiles ----
  {
    const int w = tid >> 6, lane = tid & 63;
    const int quad = lane >> 4, r16 = lane & 15;
    const int n0 = (tid >> 4) * 4;   // staging: 4 n-rows per thread
    const int d4s = (tid & 15) * 4;  // staging: 4 d-cols per thread
    const float* scan1 = scan + 8192 * 2048;

    for (int tile = b; tile < 1024; tile += gridDim.x) {
      const int dt = tile & 31;      // d-tile
      const int c  = tile >> 5;      // window
      const int d0 = dt * 64;

      f32x4 acc[4];
#pragma unroll
      for (int tn = 0; tn < 4; ++tn) acc[tn] = (f32x4){0.f, 0.f, 0.f, 0.f};

      for (int nb = 0; nb < 8; ++nb) {
        float vv[4][4];
        if (c == 0 && nb < 4) {
          const float* bp = buf + (256 + nb * 64 + n0) * 2048 + d0 + d4s;
#pragma unroll
          for (int i = 0; i < 4; ++i) {
            float4 x = *(const float4*)(bp + i * 2048);
            vv[i][0] = x.x; vv[i][1] = x.y; vv[i][2] = x.z; vv[i][3] = x.w;
          }
        } else {
          int gbase = ((c - 1) * 256 + nb * 64 + n0) * 2048 + d0 + d4s;
#pragma unroll
          for (int i = 0; i < 4; ++i) {
            float4 a = *(const float4*)(scan + gbase + i * 2048);
            float4 bb = *(const float4*)(scan1 + gbase + i * 2048);
            vv[i][0] = 0.5f * (a.x + bb.x); vv[i][1] = 0.5f * (a.y + bb.y);
            vv[i][2] = 0.5f * (a.z + bb.z); vv[i][3] = 0.5f * (a.w + bb.w);
          }
        }
        __syncthreads();   // prior iteration's fragment reads done
#pragma unroll
        for (int x = 0; x < 4; ++x) {
          bf16x4 e = {(bf16)vv[0][x], (bf16)vv[1][x], (bf16)vv[2][x], (bf16)vv[3][x]};
          *(bf16x4*)(Bs + (d4s + x) * 72 + n0) = e;
        }
        __syncthreads();

        const bf16* abase = cheb2 + (w * 16 + r16) * 512 + nb * 64 + quad * 8;
        bf16x8 a0 = *(const bf16x8*)(abase);
        bf16x8 a1 = *(const bf16x8*)(abase + 32);
#pragma unroll
        for (int ks = 0; ks < 2; ++ks) {
          bf16x8 a = ks ? a1 : a0;
#pragma unroll
          for (int tn = 0; tn < 4; ++tn) {
            bf16x8 bfr = *(const bf16x8*)(Bs + (tn * 16 + r16) * 72 + ks * 32 + quad * 8);
            acc[tn] = __builtin_amdgcn_mfma_f32_16x16x32_bf16(a, bfr, acc[tn], 0, 0, 0);
          }
        }
      }

      const float scale = 2.0f / 512.0f;
      float sq[4] = {0.f, 0.f, 0.f, 0.f};
#pragma unroll
      for (int tn = 0; tn < 4; ++tn) {
#pragma unroll
        for (int r = 0; r < 4; ++r) {
          int band = w * 16 + quad * 4 + r;
          float sc = (band == 0) ? scale * 0.5f : scale;
          float v = acc[tn][r] * sc;
          coeffs[(c * 64 + band) * 2048 + d0 + tn * 16 + r16] = v;
          sq[r] += v * v;
        }
      }
#pragma unroll
      for (int off = 8; off > 0; off >>= 1) {
#pragma unroll
        for (int r = 0; r < 4; ++r) sq[r] += __shfl_down(sq[r], off);
      }
      if (r16 == 0) {
#pragma unroll
        for (int r = 0; r < 4; ++r)
          nsq_part[(c * 64 + w * 16 + quad * 4 + r) * 32 + dt] = sq[r];
      }
    }
  }
  __threadfence();
  grid.sync();

  // ---- Phase 2: norms + bind partials (b<64) / delta (64<=b<128) ----
  if (b < 64) {
    const int c = b >> 1;
    const int half = b & 1;
    if (tid < 64) {
      float s = 0.f;
#pragma unroll
      for (int dtl = 0; dtl < 32; ++dtl) s += nsq_part[(c * 64 + tid) * 32 + dtl];
      float nrm = fmaxf(sqrtf(s), 1e-12f);
      sm64[tid] = 1.0f / nrm;
      if (half == 0) norms[c * 64 + tid] = nrm;
    }
    __syncthreads();
    const int d4 = (half * 256 + tid) * 4;
    const float wc = 0.1f * powf(0.9f, (float)(31 - c));
    float4 ar = make_float4(0.f, 0.f, 0.f, 0.f);
    float4 ai = make_float4(0.f, 0.f, 0.f, 0.f);
    for (int k = 0; k < KB_; ++k) {
      float4 cf = *(const float4*)(coeffs + (c * 64 + k) * 2048 + d4);
      float inv = sm64[k];
      float4 r = *(const float4*)(rr + k * D_MODEL + d4);
      float4 im = *(const float4*)(ri + k * D_MODEL + d4);
      float cx = cf.x * inv, cy = cf.y * inv, cz = cf.z * inv, cw = cf.w * inv;
      ar.x += cx * r.x; ar.y += cy * r.y; ar.z += cz * r.z; ar.w += cw * r.w;
      ai.x += cx * im.x; ai.y += cy * im.y; ai.z += cz * im.z; ai.w += cw * im.w;
    }
    *(float4*)(part_r + c * D_MODEL + d4) =
        make_float4(wc * ar.x, wc * ar.y, wc * ar.z, wc * ar.w);
    *(float4*)(part_i + c * D_MODEL + d4) =
        make_float4(wc * ai.x, wc * ai.y, wc * ai.z, wc * ai.w);
  } else if (b < 128) {
    const int k = b - 64;
    const float* p1 = coeffs + (31 * 64 + k) * 2048;
    const float* p0 = coeffs + (30 * 64 + k) * 2048;
    float s = 0.f;
#pragma unroll
    for (int i = 0; i < 2; ++i) {
      float4 a = *(const float4*)(p1 + tid * 4 + i * 1024);
      float4 bb = *(const float4*)(p0 + tid * 4 + i * 1024);
      float x = a.x - bb.x, y = a.y - bb.y, z = a.z - bb.z, ww = a.w - bb.w;
      s += x * x + y * y + z * z + ww * ww;
    }
    for (int o = 32; o > 0; o >>= 1) s += __shfl_down(s, o, 64);
    if ((tid & 63) == 0) red[tid >> 6] = s;
    __syncthreads();
    if (tid == 0) dout[D_MODEL + k] = sqrtf(red[0] + red[1] + red[2] + red[3]);
  }
  __threadfence();
  grid.sync();

  // ---- Phase 3: cnorm EMA + top-8 + vr/vi out + ctx ----
  if (b < 8) {
    const int d = b * 256 + tid;
    if (tid < 64) {
      float s = 0.f;
      for (int c = 0; c < NCHUNK; ++c) s = 0.9f * s + 0.1f * norms[c * 64 + tid];
      sm64[tid] = fmaxf(s, 1e-12f);
    }
    __syncthreads();
    if (tid == 0) {
      unsigned long long taken = 0ULL;
      for (int jj = 0; jj < 8; ++jj) {
        float best = -1.f;
        int bi = 0;
        for (int k = 0; k < 64; ++k) {
          float dv = dout[D_MODEL + k];
          if (!((taken >> k) & 1ULL) && dv > best) { best = dv; bi = k; }
        }
        taken |= (1ULL << bi);
        top_s[jj] = bi;
        wgt_s[jj] = log1pf(expf(wbands[bi]));  // softplus
      }
    }
    __syncthreads();
    float sr = 0.f, si = 0.f;
    for (int c = 0; c < NCHUNK; ++c) {
      sr += part_r[c * D_MODEL + d];
      si += part_i[c * D_MODEL + d];
    }
    dout[D_MODEL + KB_ + d] = sr;
    dout[D_MODEL + KB_ + D_MODEL + d] = si;
    float cx = 0.f;
#pragma unroll
    for (int jj = 0; jj < 8; ++jj) {
      int k = top_s[jj];
      cx += wgt_s[jj] * (sr * rr[k * D_MODEL + d] + si * ri[k * D_MODEL + d]) * sm64[k];
    }
    ctx[d] = cx;
  }
  __threadfence();
  grid.sync();

  // ---- Phase 4: gemv ----
  {
    const int lane = tid & 63;
    const int w = tid >> 6;
    const int row = b * 4 + w;   // 512 blocks x 4 rows = 2048
    const float* p = Wp + row * D_MODEL;
    float s = 0.f;
#pragma unroll
    for (int i = 0; i < 8; ++i) {
      int e = lane * 4 + i * 256;
      float4 wv = *(const float4*)(p + e);
      float4 cv = *(const float4*)(ctx + e);
      s += wv.x * cv.x + wv.y * cv.y + wv.z * cv.z + wv.w * cv.w;
    }
    for (int o = 32; o > 0; o >>= 1) s += __shfl_down(s, o, 64);
    if (lane == 0) {
      float sig = 1.f / (1.f + expf(-gate[0]));
      dout[row] = s * sig;
    }
  }
}

// ===========================================================================
// Fallback path: the proven R4 5-kernel pipeline (279.6 us)
// ===========================================================================
__global__ __launch_bounds__(256) void k0_prep(
    const float* __restrict__ cheby, bf16* __restrict__ cheb2)
{
  int flat = blockIdx.x * 256 + threadIdx.x;
  cheb2[flat] = (bf16)cheby[flat];
}

__global__ __launch_bounds__(256) void k1_mfma(
    const float* __restrict__ scan, const float* __restrict__ buf,
    const bf16* __restrict__ cheb2, float* __restrict__ coeffs,
    float* __restrict__ nsq_part)
{
  __shared__ bf16 Bs[64 * 72];
  const int t = threadIdx.x;
  const int dt = blockIdx.x, c = blockIdx.y;
  const int w = t >> 6, lane = t & 63;
  const int quad = lane >> 4, r16 = lane & 15;
  const int d0 = dt * 64;
  const int n0 = (t >> 4) * 4;
  const int d4s = (t & 15) * 4;
  const float* scan1 = scan + 8192 * 2048;

  f32x4 acc[4];
#pragma unroll
  for (int tn = 0; tn < 4; ++tn) acc[tn] = (f32x4){0.f, 0.f, 0.f, 0.f};

  for (int nb = 0; nb < 8; ++nb) {
    float vv[4][4];
    if (c == 0 && nb < 4) {
      const float* bp = buf + (256 + nb * 64 + n0) * 2048 + d0 + d4s;
#pragma unroll
      for (int i = 0; i < 4; ++i) {
        float4 x = *(const float4*)(bp + i * 2048);
        vv[i][0] = x.x; vv[i][1] = x.y; vv[i][2] = x.z; vv[i][3] = x.w;
      }
    } else {
      int gbase = ((c - 1) * 256 + nb * 64 + n0) * 2048 + d0 + d4s;
#pragma unroll
      for (int i = 0; i < 4; ++i) {
        float4 a = *(const float4*)(scan + gbase + i * 2048);
        float4 bb = *(const float4*)(scan1 + gbase + i * 2048);
        vv[i][0] = 0.5f * (a.x + bb.x); vv[i][1] = 0.5f * (a.y + bb.y);
        vv[i][2] = 0.5f * (a.z + bb.z); vv[i][3] = 0.5f * (a.w + bb.w);
      }
    }
    __syncthreads();
#pragma unroll
    for (int x = 0; x < 4; ++x) {
      bf16x4 e = {(bf16)vv[0][x], (bf16)vv[1][x], (bf16)vv[2][x], (bf16)vv[3][x]};
      *(bf16x4*)(Bs + (d4s + x) * 72 + n0) = e;
    }
    __syncthreads();
    const bf16* abase = cheb2 + (w * 16 + r16) * 512 + nb * 64 + quad * 8;
    bf16x8 a0 = *(const bf16x8*)(abase);
    bf16x8 a1 = *(const bf16x8*)(abase + 32);
#pragma unroll
    for (int ks = 0; ks < 2; ++ks) {
      bf16x8 a = ks ? a1 : a0;
#pragma unroll
      for (int tn = 0; tn < 4; ++tn) {
        bf16x8 bfr = *(const bf16x8*)(Bs + (tn * 16 + r16) * 72 + ks * 32 + quad * 8);
        acc[tn] = __builtin_amdgcn_mfma_f32_16x16x32_bf16(a, bfr, acc[tn], 0, 0, 0);
      }
    }
  }

  const float scale = 2.0f / 512.0f;
  float sq[4] = {0.f, 0.f, 0.f, 0.f};
#pragma unroll
  for (int tn = 0; tn < 4; ++tn) {
#pragma unroll
    for (int r = 0; r < 4; ++r) {
      int band = w * 16 + quad * 4 + r;
      float sc = (band == 0) ? scale * 0.5f : scale;
      float v = acc[tn][r] * sc;
      coeffs[(c * 64 + band) * 2048 + d0 + tn * 16 + r16] = v;
      sq[r] += v * v;
    }
  }
#pragma unroll
  for (int off = 8; off > 0; off >>= 1) {
#pragma unroll
    for (int r = 0; r < 4; ++r) sq[r] += __shfl_down(sq[r], off);
  }
  if (r16 == 0) {
#pragma unroll
    for (int r = 0; r < 4; ++r)
      nsq_part[(c * 64 + w * 16 + quad * 4 + r) * 32 + dt] = sq[r];
  }
}

__global__ __launch_bounds__(256) void k3_bind(
    const float* __restrict__ coeffs, const float* __restrict__ nsq_part,
    const float* __restrict__ rr, const float* __restrict__ ri,
    float* __restrict__ part_r, float* __restrict__ part_i,
    float* __restrict__ norms, float* __restrict__ dout)
{
  const int tid = threadIdx.x;
  const int c = blockIdx.y;
  if (blockIdx.x == 2) {
    __shared__ float red[4];
#pragma unroll
    for (int kk = 0; kk < 2; ++kk) {
      int k = c + kk * 32;
      const float* p1 = coeffs + (31 * 64 + k) * 2048;
      const float* p0 = coeffs + (30 * 64 + k) * 2048;
      float s = 0.f;
#pragma unroll
      for (int i = 0; i < 2; ++i) {
        float4 a = *(const float4*)(p1 + tid * 4 + i * 1024);
        float4 b = *(const float4*)(p0 + tid * 4 + i * 1024);
        float x = a.x - b.x, y = a.y - b.y, z = a.z - b.z, ww = a.w - b.w;
        s += x * x + y * y + z * z + ww * ww;
      }
      for (int o = 32; o > 0; o >>= 1) s += __shfl_down(s, o, 64);
      if ((tid & 63) == 0) red[tid >> 6] = s;
      __syncthreads();
      if (tid == 0) dout[D_MODEL + k] = sqrtf(red[0] + red[1] + red[2] + red[3]);
      __syncthreads();
    }
    return;
  }
  __shared__ float inv_s[64];
  if (tid < 64) {
    float s = 0.f;
#pragma unroll
    for (int dtl = 0; dtl < 32; ++dtl) s += nsq_part[(c * 64 + tid) * 32 + dtl];
    float nrm = fmaxf(sqrtf(s), 1e-12f);
    inv_s[tid] = 1.0f / nrm;
    if (blockIdx.x == 0) norms[c * 64 + tid] = nrm;
  }
  __syncthreads();
  const int d4 = (blockIdx.x * 256 + tid) * 4;
  const float wc = 0.1f * powf(0.9f, (float)(31 - c));
  float4 ar = make_float4(0.f, 0.f, 0.f, 0.f);
  float4 ai = make_float4(0.f, 0.f, 0.f, 0.f);
  for (int k = 0; k < KB_; ++k) {
    float4 cf = *(const float4*)(coeffs + (c * 64 + k) * 2048 + d4);
    float inv = inv_s[k];
    float4 r = *(const float4*)(rr + k * D_MODEL + d4);
    float4 im = *(const float4*)(ri + k * D_MODEL + d4);
    float cx = cf.x * inv, cy = cf.y * inv, cz = cf.z * inv, cw = cf.w * inv;
    ar.x += cx * r.x; ar.y += cy * r.y; ar.z += cz * r.z; ar.w += cw * r.w;
    ai.x += cx * im.x; ai.y += cy * im.y; ai.z += cz * im.z; ai.w += cw * im.w;
  }
  *(float4*)(part_r + c * D_MODEL + d4) =
      make_float4(wc * ar.x, wc * ar.y, wc * ar.z, wc * ar.w);
  *(float4*)(part_i + c * D_MODEL + d4) =
      make_float4(wc * ai.x, wc * ai.y, wc * ai.z, wc * ai.w);
}

__global__ __launch_bounds__(256) void k4_ctx(
    const float* __restrict__ norms, const float* __restrict__ part_r,
    const float* __restrict__ part_i, const float* __restrict__ rr,
    const float* __restrict__ ri, const float* __restrict__ wbands,
    float* __restrict__ dout, float* __restrict__ ctx)
{
  __shared__ float cn_s[64];
  __shared__ int top_s[8];
  __shared__ float wgt_s[8];
  const int tid = threadIdx.x;
  const int d = blockIdx.x * 256 + tid;
  if (tid < 64) {
    float s = 0.f;
    for (int c = 0; c < NCHUNK; ++c) s = 0.9f * s + 0.1f * norms[c * 64 + tid];
    cn_s[tid] = fmaxf(s, 1e-12f);
  }
  __syncthreads();
  if (tid == 0) {
    unsigned long long taken = 0ULL;
    for (int jj = 0; jj < 8; ++jj) {
      float best = -1.f;
      int bi = 0;
      for (int k = 0; k < 64; ++k) {
        float dv = dout[D_MODEL + k];
        if (!((taken >> k) & 1ULL) && dv > best) { best = dv; bi = k; }
      }
      taken |= (1ULL << bi);
      top_s[jj] = bi;
      wgt_s[jj] = log1pf(expf(wbands[bi]));
    }
  }
  __syncthreads();
  float sr = 0.f, si = 0.f;
  for (int c = 0; c < NCHUNK; ++c) {
    sr += part_r[c * D_MODEL + d];
    si += part_i[c * D_MODEL + d];
  }
  dout[D_MODEL + KB_ + d] = sr;
  dout[D_MODEL + KB_ + D_MODEL + d] = si;
  float cx = 0.f;
#pragma unroll
  for (int jj = 0; jj < 8; ++jj) {
    int k = top_s[jj];
    cx += wgt_s[jj] * (sr * rr[k * D_MODEL + d] + si * ri[k * D_MODEL + d]) * cn_s[k];
  }
  ctx[d] = cx;
}

__global__ __launch_bounds__(256) void k5b_gemv(
    const float* __restrict__ Wp, const float* __restrict__ ctx,
    const float* __restrict__ gate, float* __restrict__ dout)
{
  const int tid = threadIdx.x;
  const int lane = tid & 63;
  const int w = tid >> 6;
  const int row = blockIdx.x * 4 + w;
  const float* p = Wp + row * D_MODEL;
  float s = 0.f;
#pragma unroll
  for (int i = 0; i < 8; ++i) {
    int e = lane * 4 + i * 256;
    float4 wv = *(const float4*)(p + e);
    float4 cv = *(const float4*)(ctx + e);
    s += wv.x * cv.x + wv.y * cv.y + wv.z * cv.z + wv.w * cv.w;
  }
  for (int o = 32; o > 0; o >>= 1) s += __shfl_down(s, o, 64);
  if (lane == 0) {
    float sig = 1.f / (1.f + expf(-gate[0]));
    dout[row] = s * sig;
  }
}

extern "C" void kernel_launch(void* const* d_in, const int* in_sizes, int n_in,
                              void* d_out, int out_size, void* d_ws, size_t ws_size,
                              hipStream_t stream) {
  const float* scan  = (const float*)d_in[0];
  const float* buf   = (const float*)d_in[1];
  const float* rr    = (const float*)d_in[2];
  const float* ri    = (const float*)d_in[3];
  const float* wb    = (const float*)d_in[4];
  const float* Wp    = (const float*)d_in[5];
  const float* gate  = (const float*)d_in[6];
  const float* cheby = (const float*)d_in[7];
  float* out = (float*)d_out;
  float* ws = (float*)d_ws;

  float* coeffs   = ws + OFF_COEFFS;
  float* nsq_part = ws + OFF_NSQ;
  float* norms    = ws + OFF_NORMS;
  float* part_r   = ws + OFF_PARTR;
  float* part_i   = ws + OFF_PARTI;
  float* ctx      = ws + OFF_CTX;
  bf16*  cheb2    = (bf16*)(ws + OFF_CHEB2);

  // can we co-reside 512 blocks (2/CU on 256 CUs)?
  int maxB = 0;
  hipError_t qerr = hipOccupancyMaxActiveBlocksPerMultiprocessor(
      &maxB, fused_all, 256, 0);
  bool coop_ok = (qerr == hipSuccess && maxB >= 2);

  if (coop_ok) {
    void* args[] = {
      (void*)&scan, (void*)&buf, (void*)&rr, (void*)&ri, (void*)&wb,
      (void*)&Wp, (void*)&gate, (void*)&cheby, (void*)&out,
      (void*)&coeffs, (void*)&nsq_part, (void*)&norms,
      (void*)&part_r, (void*)&part_i, (void*)&ctx, (void*)&cheb2
    };
    hipError_t lerr = hipLaunchCooperativeKernel(
        (const void*)fused_all, dim3(512), dim3(256), args, 0, stream);
    if (lerr == hipSuccess) return;
  }

  // fallback: proven R4 pipeline
  k0_prep<<<128, 256, 0, stream>>>(cheby, cheb2);
  k1_mfma<<<dim3(32, 32), 256, 0, stream>>>(scan, buf, cheb2, coeffs, nsq_part);
  k3_bind<<<dim3(3, NCHUNK), 256, 0, stream>>>(coeffs, nsq_part, rr, ri,
                                               part_r, part_i, norms, out);
  k4_ctx<<<8, 256, 0, stream>>>(norms, part_r, part_i, rr, ri, wb, out, ctx);
  k5b_gemv<<<512, 256, 0, stream>>>(Wp, ctx, gate, out);
}